// Round 1
// baseline (2082.443 us; speedup 1.0000x reference)
//
#include <hip/hip_runtime.h>

#define NN 50000
#define NE 1600000
#define PER_GRAPH 5000
#define TDIM 10
#define INCH 2
#define D0 12
#define HID 128

// ---------------- graph preprocessing ----------------

__global__ void k_init(int* __restrict__ deg, int* __restrict__ fill) {
  int i = blockIdx.x * blockDim.x + threadIdx.x;
  if (i < NN) { deg[i] = 1; fill[i] = 0; }   // deg starts at 1 (self loop)
}

__global__ void k_count(const int* __restrict__ dst, int* __restrict__ deg) {
  int e = blockIdx.x * blockDim.x + threadIdx.x;
  if (e < NE) atomicAdd(&deg[dst[e]], 1);
}

__global__ void k_dinv(const int* __restrict__ deg, float* __restrict__ dinv) {
  int i = blockIdx.x * blockDim.x + threadIdx.x;
  if (i < NN) dinv[i] = rsqrtf((float)deg[i]);   // deg >= 1 always
}

// exclusive scan of (deg-1) -> rowptr, single block, wave-scan based
__global__ __launch_bounds__(1024) void k_scan(const int* __restrict__ deg,
                                               int* __restrict__ rowptr) {
  __shared__ int wsum[16];
  __shared__ int carry_s;
  int tid = threadIdx.x;
  int lane = tid & 63, wid = tid >> 6;
  if (tid == 0) carry_s = 0;
  __syncthreads();
  for (int base = 0; base < NN; base += 1024) {
    int i = base + tid;
    int v = (i < NN) ? deg[i] - 1 : 0;
    int x = v;
    #pragma unroll
    for (int off = 1; off < 64; off <<= 1) {
      int t = __shfl_up(x, off, 64);
      if (lane >= off) x += t;
    }
    if (lane == 63) wsum[wid] = x;
    __syncthreads();
    if (wid == 0) {
      int w = (lane < 16) ? wsum[lane] : 0;
      #pragma unroll
      for (int off = 1; off < 16; off <<= 1) {
        int t = __shfl_up(w, off, 64);
        if (lane >= off) w += t;
      }
      if (lane < 16) wsum[lane] = w;
    }
    __syncthreads();
    int wbase = wid ? wsum[wid - 1] : 0;
    int incl = wbase + x;
    int c = carry_s;
    if (i < NN) rowptr[i] = c + incl - v;   // exclusive
    int total = wsum[15];
    __syncthreads();
    if (tid == 0) carry_s = c + total;
    __syncthreads();
  }
  if (tid == 0) rowptr[NN] = carry_s;
}

__global__ void k_fill(const int* __restrict__ src, const int* __restrict__ dst,
                       const int* __restrict__ rowptr, int* __restrict__ fill,
                       int* __restrict__ col) {
  int e = blockIdx.x * blockDim.x + threadIdx.x;
  if (e < NE) {
    int d = dst[e];
    int pos = atomicAdd(&fill[d], 1);
    col[rowptr[d] + pos] = src[e];
  }
}

// ---------------- feature construction ----------------

__global__ void k_eps0(const float* __restrict__ x_t, const int* __restrict__ t,
                       const float* __restrict__ t_emb, float* __restrict__ eps0) {
  int idx = blockIdx.x * blockDim.x + threadIdx.x;
  if (idx >= NN * D0) return;
  int i = idx / D0, f = idx - i * D0;
  float v;
  if (f < INCH) v = x_t[i * INCH + f];
  else          v = t_emb[t[i / PER_GRAPH] * TDIM + (f - INCH)];
  eps0[idx] = v;
}

// ---------------- SpMM (Â x) ----------------

__global__ __launch_bounds__(256) void k_spmm12(const float* __restrict__ x,
    const int* __restrict__ rowptr, const int* __restrict__ col,
    const float* __restrict__ dinv, float* __restrict__ xp) {
  int node = blockIdx.x * 4 + (threadIdx.x >> 6);
  if (node >= NN) return;
  int lane = threadIdx.x & 63;
  float di = dinv[node];
  float acc = 0.f;
  if (lane < D0) acc = di * x[node * D0 + lane];
  int beg = rowptr[node], end = rowptr[node + 1];
  for (int p = beg; p < end; ++p) {
    int s = col[p];
    float w = dinv[s];
    if (lane < D0) acc += w * x[s * D0 + lane];
  }
  if (lane < D0) xp[node * D0 + lane] = acc * di;
}

__global__ __launch_bounds__(256) void k_spmm128(const float* __restrict__ x,
    const int* __restrict__ rowptr, const int* __restrict__ col,
    const float* __restrict__ dinv, float* __restrict__ xp) {
  int node = blockIdx.x * 4 + (threadIdx.x >> 6);
  if (node >= NN) return;
  int lane = threadIdx.x & 63;
  float di = dinv[node];
  float2 v = *(const float2*)(x + (size_t)node * HID + lane * 2);
  float ax = di * v.x, ay = di * v.y;
  int beg = rowptr[node], end = rowptr[node + 1];
  for (int p = beg; p < end; ++p) {
    int s = col[p];
    float w = dinv[s];
    float2 u = *(const float2*)(x + (size_t)s * HID + lane * 2);
    ax += w * u.x; ay += w * u.y;
  }
  float2 o = { ax * di, ay * di };
  *(float2*)(xp + (size_t)node * HID + lane * 2) = o;
}

// ---------------- dual GEMM: out = relu(A0 @ W[0] + A1 @ W[1] + b0 + b1) ----------------
// W is contiguous (2, KPART, 128). Tile: 64 rows x 128 cols, 256 threads.

template<int KPART, int BK>
__global__ __launch_bounds__(256) void k_gemm(const float* __restrict__ A0,
    const float* __restrict__ A1, const float* __restrict__ W,
    const float* __restrict__ b0, const float* __restrict__ b1,
    float* __restrict__ out) {
  __shared__ __align__(16) float As[BK][64];
  __shared__ __align__(16) float Bs[BK][128];
  int tid = threadIdx.x;
  int tx = tid & 31, ty = tid >> 5;        // tx: 32 col groups of 4, ty: 8 row groups of 8
  int row0 = blockIdx.x * 64;
  float acc[8][4] = {};
  #pragma unroll
  for (int part = 0; part < 2; ++part) {
    const float* A = part ? A1 : A0;
    const float* Wp = W + (size_t)part * KPART * 128;
    for (int k0 = 0; k0 < KPART; k0 += BK) {
      __syncthreads();
      if constexpr (BK == 16) {
        int m = tid >> 2, ks = (tid & 3) << 2;
        int r = row0 + m;
        float4 v = { 0, 0, 0, 0 };
        if (r < NN) v = *(const float4*)&A[(size_t)r * KPART + k0 + ks];
        As[ks][m] = v.x; As[ks + 1][m] = v.y; As[ks + 2][m] = v.z; As[ks + 3][m] = v.w;
      } else {
        for (int e = tid; e < 64 * BK; e += 256) {
          int m = e / BK, kk = e - m * BK;
          int r = row0 + m;
          As[kk][m] = (r < NN) ? A[(size_t)r * KPART + k0 + kk] : 0.f;
        }
      }
      for (int e2 = tid; e2 < BK * 64; e2 += 256) {
        int kk = e2 >> 6, n2 = (e2 & 63) << 1;
        *(float2*)&Bs[kk][n2] = *(const float2*)&Wp[(size_t)(k0 + kk) * 128 + n2];
      }
      __syncthreads();
      #pragma unroll
      for (int kk = 0; kk < BK; ++kk) {
        float4 a0 = *(const float4*)&As[kk][ty * 8];
        float4 a1 = *(const float4*)&As[kk][ty * 8 + 4];
        float4 bv = *(const float4*)&Bs[kk][tx * 4];
        float am[8] = { a0.x, a0.y, a0.z, a0.w, a1.x, a1.y, a1.z, a1.w };
        #pragma unroll
        for (int i = 0; i < 8; ++i) {
          acc[i][0] += am[i] * bv.x;
          acc[i][1] += am[i] * bv.y;
          acc[i][2] += am[i] * bv.z;
          acc[i][3] += am[i] * bv.w;
        }
      }
    }
  }
  float bx = b0[tx * 4 + 0] + b1[tx * 4 + 0];
  float by = b0[tx * 4 + 1] + b1[tx * 4 + 1];
  float bz = b0[tx * 4 + 2] + b1[tx * 4 + 2];
  float bw = b0[tx * 4 + 3] + b1[tx * 4 + 3];
  #pragma unroll
  for (int i = 0; i < 8; ++i) {
    int r = row0 + ty * 8 + i;
    if (r < NN) {
      float4 o;
      o.x = fmaxf(acc[i][0] + bx, 0.f);
      o.y = fmaxf(acc[i][1] + by, 0.f);
      o.z = fmaxf(acc[i][2] + bz, 0.f);
      o.w = fmaxf(acc[i][3] + bw, 0.f);
      *(float4*)&out[(size_t)r * 128 + tx * 4] = o;
    }
  }
}

// ---------------- output layer (N=2) ----------------

__global__ __launch_bounds__(256) void k_out(const float* __restrict__ h,
    const float* __restrict__ xp, const float* __restrict__ Wo,
    const float* __restrict__ bo, float* __restrict__ out) {
  int node = blockIdx.x * 4 + (threadIdx.x >> 6);
  if (node >= NN) return;
  int lane = threadIdx.x & 63;
  float a0 = 0.f, a1 = 0.f;
  #pragma unroll
  for (int tph = 0; tph < 2; ++tph) {
    int k = lane + tph * 64;
    float hv = h[(size_t)node * HID + k];
    float xv = xp[(size_t)node * HID + k];
    a0 += hv * Wo[k * 2 + 0] + xv * Wo[256 + k * 2 + 0];
    a1 += hv * Wo[k * 2 + 1] + xv * Wo[256 + k * 2 + 1];
  }
  #pragma unroll
  for (int off = 32; off; off >>= 1) {
    a0 += __shfl_down(a0, off, 64);
    a1 += __shfl_down(a1, off, 64);
  }
  if (lane == 0) {
    out[node * 2 + 0] = fmaxf(a0 + bo[0] + bo[2], 0.f);
    out[node * 2 + 1] = fmaxf(a1 + bo[1] + bo[3], 0.f);
  }
}

// ---------------- launcher ----------------

extern "C" void kernel_launch(void* const* d_in, const int* in_sizes, int n_in,
                              void* d_out, int out_size, void* d_ws, size_t ws_size,
                              hipStream_t stream) {
  const float* x_t   = (const float*)d_in[0];
  const int*   eidx  = (const int*)d_in[1];
  const int*   t     = (const int*)d_in[2];
  const float* t_emb = (const float*)d_in[3];
  const float* W_in  = (const float*)d_in[4];
  const float* b_in  = (const float*)d_in[5];
  const float* W_hid = (const float*)d_in[6];
  const float* b_hid = (const float*)d_in[7];
  const float* W_out = (const float*)d_in[8];
  const float* b_out = (const float*)d_in[9];
  float* out = (float*)d_out;

  char* ws = (char*)d_ws;
  size_t off = 0;
  auto take = [&](size_t bytes) {
    char* p = ws + off;
    off += (bytes + 255) & ~(size_t)255;
    return p;
  };
  int*   deg    = (int*)take((size_t)NN * 4);
  int*   fill   = (int*)take((size_t)NN * 4);
  int*   rowptr = (int*)take((size_t)(NN + 1) * 4);
  float* dinv   = (float*)take((size_t)NN * 4);
  int*   col    = (int*)take((size_t)NE * 4);
  float* eps0   = (float*)take((size_t)NN * D0 * 4);
  float* xp0    = (float*)take((size_t)NN * D0 * 4);
  float* h0     = (float*)take((size_t)NN * HID * 4);
  float* h1     = (float*)take((size_t)NN * HID * 4);
  float* xp     = (float*)take((size_t)NN * HID * 4);

  const int* src = eidx;
  const int* dst = eidx + NE;

  hipLaunchKernelGGL(k_init,  dim3((NN + 255) / 256), dim3(256), 0, stream, deg, fill);
  hipLaunchKernelGGL(k_count, dim3((NE + 255) / 256), dim3(256), 0, stream, dst, deg);
  hipLaunchKernelGGL(k_dinv,  dim3((NN + 255) / 256), dim3(256), 0, stream, deg, dinv);
  hipLaunchKernelGGL(k_scan,  dim3(1), dim3(1024), 0, stream, deg, rowptr);
  hipLaunchKernelGGL(k_fill,  dim3((NE + 255) / 256), dim3(256), 0, stream, src, dst, rowptr, fill, col);
  hipLaunchKernelGGL(k_eps0,  dim3((NN * D0 + 255) / 256), dim3(256), 0, stream, x_t, t, t_emb, eps0);

  // layer 1: 12 -> 128
  hipLaunchKernelGGL(k_spmm12, dim3((NN + 3) / 4), dim3(256), 0, stream, eps0, rowptr, col, dinv, xp0);
  hipLaunchKernelGGL((k_gemm<12, 12>), dim3((NN + 63) / 64), dim3(256), 0, stream,
                     eps0, xp0, W_in, b_in, b_in + 128, h0);

  // 7 hidden layers: 128 -> 128
  float* cur = h0;
  float* nxt = h1;
  for (int i = 0; i < 7; ++i) {
    hipLaunchKernelGGL(k_spmm128, dim3((NN + 3) / 4), dim3(256), 0, stream, cur, rowptr, col, dinv, xp);
    hipLaunchKernelGGL((k_gemm<128, 16>), dim3((NN + 63) / 64), dim3(256), 0, stream,
                       cur, xp, W_hid + (size_t)i * 2 * 128 * 128,
                       b_hid + (size_t)i * 2 * 128, b_hid + (size_t)i * 2 * 128 + 128, nxt);
    float* tmp = cur; cur = nxt; nxt = tmp;
  }

  // output layer: 128 -> 2
  hipLaunchKernelGGL(k_spmm128, dim3((NN + 3) / 4), dim3(256), 0, stream, cur, rowptr, col, dinv, xp);
  hipLaunchKernelGGL(k_out, dim3((NN + 3) / 4), dim3(256), 0, stream, cur, xp, W_out, b_out, out);
}

// Round 4
// 1657.887 us; speedup vs baseline: 1.2561x; 1.2561x over previous
//
#include <hip/hip_runtime.h>

#define NN 50000
#define NE 1600000
#define PER_GRAPH 5000
#define TDIM 10
#define INCH 2
#define D0 12
#define HID 128

// ---------------- graph preprocessing ----------------

__global__ void k_init(int* __restrict__ deg, int* __restrict__ fill) {
  int i = blockIdx.x * blockDim.x + threadIdx.x;
  if (i < NN) { deg[i] = 1; fill[i] = 0; }   // deg starts at 1 (self loop)
}

__global__ void k_count(const int* __restrict__ dst, int* __restrict__ deg) {
  int e = blockIdx.x * blockDim.x + threadIdx.x;
  if (e < NE) atomicAdd(&deg[dst[e]], 1);
}

__global__ void k_dinv(const int* __restrict__ deg, float* __restrict__ dinv) {
  int i = blockIdx.x * blockDim.x + threadIdx.x;
  if (i < NN) dinv[i] = rsqrtf((float)deg[i]);   // deg >= 1 always
}

// exclusive scan of (deg-1) -> rowptr, single block, wave-scan based
__global__ __launch_bounds__(1024) void k_scan(const int* __restrict__ deg,
                                               int* __restrict__ rowptr) {
  __shared__ int wsum[16];
  __shared__ int carry_s;
  int tid = threadIdx.x;
  int lane = tid & 63, wid = tid >> 6;
  if (tid == 0) carry_s = 0;
  __syncthreads();
  for (int base = 0; base < NN; base += 1024) {
    int i = base + tid;
    int v = (i < NN) ? deg[i] - 1 : 0;
    int x = v;
    #pragma unroll
    for (int off = 1; off < 64; off <<= 1) {
      int t = __shfl_up(x, off, 64);
      if (lane >= off) x += t;
    }
    if (lane == 63) wsum[wid] = x;
    __syncthreads();
    if (wid == 0) {
      int w = (lane < 16) ? wsum[lane] : 0;
      #pragma unroll
      for (int off = 1; off < 16; off <<= 1) {
        int t = __shfl_up(w, off, 64);
        if (lane >= off) w += t;
      }
      if (lane < 16) wsum[lane] = w;
    }
    __syncthreads();
    int wbase = wid ? wsum[wid - 1] : 0;
    int incl = wbase + x;
    int c = carry_s;
    if (i < NN) rowptr[i] = c + incl - v;   // exclusive
    int total = wsum[15];
    __syncthreads();
    if (tid == 0) carry_s = c + total;
    __syncthreads();
  }
  if (tid == 0) rowptr[NN] = carry_s;
}

__global__ void k_fill(const int* __restrict__ src, const int* __restrict__ dst,
                       const int* __restrict__ rowptr, int* __restrict__ fill,
                       int* __restrict__ col) {
  int e = blockIdx.x * blockDim.x + threadIdx.x;
  if (e < NE) {
    int d = dst[e];
    int pos = atomicAdd(&fill[d], 1);
    col[rowptr[d] + pos] = src[e];
  }
}

// ---------------- feature construction ----------------

__global__ void k_eps0(const float* __restrict__ x_t, const int* __restrict__ t,
                       const float* __restrict__ t_emb, float* __restrict__ eps0) {
  int idx = blockIdx.x * blockDim.x + threadIdx.x;
  if (idx >= NN * D0) return;
  int i = idx / D0, f = idx - i * D0;
  float v;
  if (f < INCH) v = x_t[i * INCH + f];
  else          v = t_emb[t[i / PER_GRAPH] * TDIM + (f - INCH)];
  eps0[idx] = v;
}

// ---------------- SpMM (Â x) ----------------

__global__ __launch_bounds__(256) void k_spmm12(const float* __restrict__ x,
    const int* __restrict__ rowptr, const int* __restrict__ col,
    const float* __restrict__ dinv, float* __restrict__ xp) {
  int node = blockIdx.x * 4 + (threadIdx.x >> 6);
  if (node >= NN) return;
  int lane = threadIdx.x & 63;
  float di = dinv[node];
  float acc = 0.f;
  if (lane < D0) acc = di * x[node * D0 + lane];
  int beg = rowptr[node], end = rowptr[node + 1];
  for (int p = beg; p < end; ++p) {
    int s = col[p];
    float w = dinv[s];
    if (lane < D0) acc += w * x[s * D0 + lane];
  }
  if (lane < D0) xp[node * D0 + lane] = acc * di;
}

// half-wave (32 lanes, float4) per edge; 2 edges per wave concurrently;
// inner loop unrolled x4 -> up to 8 independent 512B row loads in flight/wave.
__global__ __launch_bounds__(256) void k_spmm128(const float* __restrict__ x,
    const int* __restrict__ rowptr, const int* __restrict__ col,
    const float* __restrict__ dinv, float* __restrict__ xp) {
  int node = blockIdx.x * 4 + (threadIdx.x >> 6);
  if (node >= NN) return;
  int lane = threadIdx.x & 63;
  int half = lane >> 5;        // 0 or 1
  int l32  = lane & 31;        // float4 chunk index within the 128-float row
  const float4* __restrict__ xr = (const float4*)x;
  float di = dinv[node];
  float4 acc = { 0.f, 0.f, 0.f, 0.f };
  if (!half) {
    float4 v = xr[(size_t)node * 32 + l32];   // self-loop term
    acc.x = di * v.x; acc.y = di * v.y; acc.z = di * v.z; acc.w = di * v.w;
  }
  int beg = rowptr[node], end = rowptr[node + 1];
  int cnt = end - beg;
  int mid = beg + ((cnt + 1) >> 1);
  int p  = half ? mid : beg;
  int pe = half ? end : mid;
  // unrolled x4 with prefetched indices: 4 independent gathers per half-wave
  for (; p + 4 <= pe; p += 4) {
    int s0 = col[p], s1 = col[p + 1], s2 = col[p + 2], s3 = col[p + 3];
    float w0 = dinv[s0], w1 = dinv[s1], w2 = dinv[s2], w3 = dinv[s3];
    float4 u0 = xr[(size_t)s0 * 32 + l32];
    float4 u1 = xr[(size_t)s1 * 32 + l32];
    float4 u2 = xr[(size_t)s2 * 32 + l32];
    float4 u3 = xr[(size_t)s3 * 32 + l32];
    acc.x += w0 * u0.x; acc.y += w0 * u0.y; acc.z += w0 * u0.z; acc.w += w0 * u0.w;
    acc.x += w1 * u1.x; acc.y += w1 * u1.y; acc.z += w1 * u1.z; acc.w += w1 * u1.w;
    acc.x += w2 * u2.x; acc.y += w2 * u2.y; acc.z += w2 * u2.z; acc.w += w2 * u2.w;
    acc.x += w3 * u3.x; acc.y += w3 * u3.y; acc.z += w3 * u3.z; acc.w += w3 * u3.w;
  }
  for (; p < pe; ++p) {
    int s = col[p];
    float w = dinv[s];
    float4 u = xr[(size_t)s * 32 + l32];
    acc.x += w * u.x; acc.y += w * u.y; acc.z += w * u.z; acc.w += w * u.w;
  }
  // combine the two halves: lane i and lane i^32 hold the same feature chunk
  float4 oth;
  oth.x = __shfl(acc.x, lane ^ 32, 64);
  oth.y = __shfl(acc.y, lane ^ 32, 64);
  oth.z = __shfl(acc.z, lane ^ 32, 64);
  oth.w = __shfl(acc.w, lane ^ 32, 64);
  if (!half) {
    float4 o;
    o.x = (acc.x + oth.x) * di;
    o.y = (acc.y + oth.y) * di;
    o.z = (acc.z + oth.z) * di;
    o.w = (acc.w + oth.w) * di;
    ((float4*)xp)[(size_t)node * 32 + l32] = o;
  }
}

// ---------------- dual GEMM (12 -> 128), 64x128 tile ----------------

template<int KPART, int BK>
__global__ __launch_bounds__(256) void k_gemm(const float* __restrict__ A0,
    const float* __restrict__ A1, const float* __restrict__ W,
    const float* __restrict__ b0, const float* __restrict__ b1,
    float* __restrict__ out) {
  __shared__ __align__(16) float As[BK][64];
  __shared__ __align__(16) float Bs[BK][128];
  int tid = threadIdx.x;
  int tx = tid & 31, ty = tid >> 5;
  int row0 = blockIdx.x * 64;
  float acc[8][4] = {};
  for (int part = 0; part < 2; ++part) {
    const float* A = part ? A1 : A0;
    const float* Wp = W + (size_t)part * KPART * 128;
    for (int k0 = 0; k0 < KPART; k0 += BK) {
      __syncthreads();
      for (int e = tid; e < 64 * BK; e += 256) {
        int m = e / BK, kk = e - m * BK;
        int r = row0 + m;
        As[kk][m] = (r < NN) ? A[(size_t)r * KPART + k0 + kk] : 0.f;
      }
      for (int e2 = tid; e2 < BK * 64; e2 += 256) {
        int kk = e2 >> 6, n2 = (e2 & 63) << 1;
        *(float2*)&Bs[kk][n2] = *(const float2*)&Wp[(size_t)(k0 + kk) * 128 + n2];
      }
      __syncthreads();
      #pragma unroll
      for (int kk = 0; kk < BK; ++kk) {
        float4 a0 = *(const float4*)&As[kk][ty * 8];
        float4 a1 = *(const float4*)&As[kk][ty * 8 + 4];
        float4 bv = *(const float4*)&Bs[kk][tx * 4];
        float am[8] = { a0.x, a0.y, a0.z, a0.w, a1.x, a1.y, a1.z, a1.w };
        #pragma unroll
        for (int i = 0; i < 8; ++i) {
          acc[i][0] += am[i] * bv.x;
          acc[i][1] += am[i] * bv.y;
          acc[i][2] += am[i] * bv.z;
          acc[i][3] += am[i] * bv.w;
        }
      }
    }
  }
  float bx = b0[tx * 4 + 0] + b1[tx * 4 + 0];
  float by = b0[tx * 4 + 1] + b1[tx * 4 + 1];
  float bz = b0[tx * 4 + 2] + b1[tx * 4 + 2];
  float bw = b0[tx * 4 + 3] + b1[tx * 4 + 3];
  #pragma unroll
  for (int i = 0; i < 8; ++i) {
    int r = row0 + ty * 8 + i;
    if (r < NN) {
      float4 o;
      o.x = fmaxf(acc[i][0] + bx, 0.f);
      o.y = fmaxf(acc[i][1] + by, 0.f);
      o.z = fmaxf(acc[i][2] + bz, 0.f);
      o.w = fmaxf(acc[i][3] + bw, 0.f);
      *(float4*)&out[(size_t)r * 128 + tx * 4] = o;
    }
  }
}

// ---------------- dual GEMM (128 -> 128), 128x128 tile, 8x8 acc ----------------
// part/k0 kept as RUNTIME loops (compile-size discipline); only kk unrolled.

__global__ __launch_bounds__(256) void k_gemm128(const float* __restrict__ A0,
    const float* __restrict__ A1, const float* __restrict__ W,
    const float* __restrict__ b0, const float* __restrict__ b1,
    float* __restrict__ out) {
  constexpr int BK = 16;
  __shared__ __align__(16) float As[BK][128];
  __shared__ __align__(16) float Bs[BK][128];
  int tid = threadIdx.x;
  int tx = tid & 15;           // 16 col groups; cols tx*4..+3 and 64+tx*4..+3
  int ty = tid >> 4;           // 16 row groups of 8
  int row0 = blockIdx.x * 128;
  float acc[8][8] = {};

  int lm = tid >> 1;                 // A-load row 0..127
  int lk = (tid & 1) * 8;            // A-load k offset 0 or 8

  for (int part = 0; part < 2; ++part) {
    const float* A = part ? A1 : A0;
    const float* Wp = W + (size_t)part * 128 * 128;
    for (int k0 = 0; k0 < 128; k0 += BK) {
      __syncthreads();
      // stage A: 128 rows x 16 k, transposed into As[k][m]
      {
        int r = row0 + lm;
        float4 v0 = { 0, 0, 0, 0 }, v1 = { 0, 0, 0, 0 };
        if (r < NN) {
          v0 = *(const float4*)&A[(size_t)r * 128 + k0 + lk];
          v1 = *(const float4*)&A[(size_t)r * 128 + k0 + lk + 4];
        }
        As[lk + 0][lm] = v0.x; As[lk + 1][lm] = v0.y;
        As[lk + 2][lm] = v0.z; As[lk + 3][lm] = v0.w;
        As[lk + 4][lm] = v1.x; As[lk + 5][lm] = v1.y;
        As[lk + 6][lm] = v1.z; As[lk + 7][lm] = v1.w;
      }
      // stage B: 16 k x 128 cols, row-major copy (coalesced float4)
      {
        int i0 = tid;                 // float4 index 0..255
        int kk = i0 >> 5, n4 = (i0 & 31) << 2;
        *(float4*)&Bs[kk][n4] = *(const float4*)&Wp[(size_t)(k0 + kk) * 128 + n4];
        int i1 = tid + 256;
        kk = i1 >> 5; n4 = (i1 & 31) << 2;
        *(float4*)&Bs[kk][n4] = *(const float4*)&Wp[(size_t)(k0 + kk) * 128 + n4];
      }
      __syncthreads();
      #pragma unroll
      for (int kk = 0; kk < BK; ++kk) {
        float4 a0 = *(const float4*)&As[kk][ty * 8];
        float4 a1 = *(const float4*)&As[kk][ty * 8 + 4];
        float4 bv0 = *(const float4*)&Bs[kk][tx * 4];
        float4 bv1 = *(const float4*)&Bs[kk][64 + tx * 4];
        float am[8] = { a0.x, a0.y, a0.z, a0.w, a1.x, a1.y, a1.z, a1.w };
        float bn[8] = { bv0.x, bv0.y, bv0.z, bv0.w, bv1.x, bv1.y, bv1.z, bv1.w };
        #pragma unroll
        for (int i = 0; i < 8; ++i)
          #pragma unroll
          for (int j = 0; j < 8; ++j)
            acc[i][j] += am[i] * bn[j];
      }
    }
  }
  float bias[8];
  #pragma unroll
  for (int j = 0; j < 4; ++j) {
    bias[j]     = b0[tx * 4 + j]      + b1[tx * 4 + j];
    bias[4 + j] = b0[64 + tx * 4 + j] + b1[64 + tx * 4 + j];
  }
  #pragma unroll
  for (int i = 0; i < 8; ++i) {
    int r = row0 + ty * 8 + i;
    if (r < NN) {
      float4 o0, o1;
      o0.x = fmaxf(acc[i][0] + bias[0], 0.f);
      o0.y = fmaxf(acc[i][1] + bias[1], 0.f);
      o0.z = fmaxf(acc[i][2] + bias[2], 0.f);
      o0.w = fmaxf(acc[i][3] + bias[3], 0.f);
      o1.x = fmaxf(acc[i][4] + bias[4], 0.f);
      o1.y = fmaxf(acc[i][5] + bias[5], 0.f);
      o1.z = fmaxf(acc[i][6] + bias[6], 0.f);
      o1.w = fmaxf(acc[i][7] + bias[7], 0.f);
      *(float4*)&out[(size_t)r * 128 + tx * 4] = o0;
      *(float4*)&out[(size_t)r * 128 + 64 + tx * 4] = o1;
    }
  }
}

// ---------------- output layer (N=2) ----------------

__global__ __launch_bounds__(256) void k_out(const float* __restrict__ h,
    const float* __restrict__ xp, const float* __restrict__ Wo,
    const float* __restrict__ bo, float* __restrict__ out) {
  int node = blockIdx.x * 4 + (threadIdx.x >> 6);
  if (node >= NN) return;
  int lane = threadIdx.x & 63;
  float a0 = 0.f, a1 = 0.f;
  #pragma unroll
  for (int tph = 0; tph < 2; ++tph) {
    int k = lane + tph * 64;
    float hv = h[(size_t)node * HID + k];
    float xv = xp[(size_t)node * HID + k];
    a0 += hv * Wo[k * 2 + 0] + xv * Wo[256 + k * 2 + 0];
    a1 += hv * Wo[k * 2 + 1] + xv * Wo[256 + k * 2 + 1];
  }
  #pragma unroll
  for (int off = 32; off; off >>= 1) {
    a0 += __shfl_down(a0, off, 64);
    a1 += __shfl_down(a1, off, 64);
  }
  if (lane == 0) {
    out[node * 2 + 0] = fmaxf(a0 + bo[0] + bo[2], 0.f);
    out[node * 2 + 1] = fmaxf(a1 + bo[1] + bo[3], 0.f);
  }
}

// ---------------- launcher ----------------

extern "C" void kernel_launch(void* const* d_in, const int* in_sizes, int n_in,
                              void* d_out, int out_size, void* d_ws, size_t ws_size,
                              hipStream_t stream) {
  const float* x_t   = (const float*)d_in[0];
  const int*   eidx  = (const int*)d_in[1];
  const int*   t     = (const int*)d_in[2];
  const float* t_emb = (const float*)d_in[3];
  const float* W_in  = (const float*)d_in[4];
  const float* b_in  = (const float*)d_in[5];
  const float* W_hid = (const float*)d_in[6];
  const float* b_hid = (const float*)d_in[7];
  const float* W_out = (const float*)d_in[8];
  const float* b_out = (const float*)d_in[9];
  float* out = (float*)d_out;

  char* ws = (char*)d_ws;
  size_t off = 0;
  auto take = [&](size_t bytes) {
    char* p = ws + off;
    off += (bytes + 255) & ~(size_t)255;
    return p;
  };
  int*   deg    = (int*)take((size_t)NN * 4);
  int*   fill   = (int*)take((size_t)NN * 4);
  int*   rowptr = (int*)take((size_t)(NN + 1) * 4);
  float* dinv   = (float*)take((size_t)NN * 4);
  int*   col    = (int*)take((size_t)NE * 4);
  float* eps0   = (float*)take((size_t)NN * D0 * 4);
  float* xp0    = (float*)take((size_t)NN * D0 * 4);
  float* h0     = (float*)take((size_t)NN * HID * 4);
  float* h1     = (float*)take((size_t)NN * HID * 4);
  float* xp     = (float*)take((size_t)NN * HID * 4);

  const int* src = eidx;
  const int* dst = eidx + NE;

  hipLaunchKernelGGL(k_init,  dim3((NN + 255) / 256), dim3(256), 0, stream, deg, fill);
  hipLaunchKernelGGL(k_count, dim3((NE + 255) / 256), dim3(256), 0, stream, dst, deg);
  hipLaunchKernelGGL(k_dinv,  dim3((NN + 255) / 256), dim3(256), 0, stream, deg, dinv);
  hipLaunchKernelGGL(k_scan,  dim3(1), dim3(1024), 0, stream, deg, rowptr);
  hipLaunchKernelGGL(k_fill,  dim3((NE + 255) / 256), dim3(256), 0, stream, src, dst, rowptr, fill, col);
  hipLaunchKernelGGL(k_eps0,  dim3((NN * D0 + 255) / 256), dim3(256), 0, stream, x_t, t, t_emb, eps0);

  // layer 1: 12 -> 128
  hipLaunchKernelGGL(k_spmm12, dim3((NN + 3) / 4), dim3(256), 0, stream, eps0, rowptr, col, dinv, xp0);
  hipLaunchKernelGGL((k_gemm<12, 12>), dim3((NN + 63) / 64), dim3(256), 0, stream,
                     eps0, xp0, W_in, b_in, b_in + 128, h0);

  // 7 hidden layers: 128 -> 128
  float* cur = h0;
  float* nxt = h1;
  for (int i = 0; i < 7; ++i) {
    hipLaunchKernelGGL(k_spmm128, dim3((NN + 3) / 4), dim3(256), 0, stream, cur, rowptr, col, dinv, xp);
    hipLaunchKernelGGL(k_gemm128, dim3((NN + 127) / 128), dim3(256), 0, stream,
                       cur, xp, W_hid + (size_t)i * 2 * 128 * 128,
                       b_hid + (size_t)i * 2 * 128, b_hid + (size_t)i * 2 * 128 + 128, nxt);
    float* tmp = cur; cur = nxt; nxt = tmp;
  }

  // output layer: 128 -> 2
  hipLaunchKernelGGL(k_spmm128, dim3((NN + 3) / 4), dim3(256), 0, stream, cur, rowptr, col, dinv, xp);
  hipLaunchKernelGGL(k_out, dim3((NN + 3) / 4), dim3(256), 0, stream, cur, xp, W_out, b_out, out);
}